// Round 1
// baseline (1229.287 us; speedup 1.0000x reference)
//
#include <hip/hip_runtime.h>
#include <hip/hip_bf16.h>
#include <math.h>

#define NH 4      // heads
#define OE 16     // OUT_E
#define ON 32     // OUT_N
#define INN 128   // IN_N
#define INE 32    // IN_E
#define HOE 64    // NH*OE
#define HON 128   // NH*ON

// ---------------- K0: zero int32 buffer ----------------
__global__ void k_zero_i32(int* __restrict__ p, int n) {
    int i = blockIdx.x * blockDim.x + threadIdx.x;
    int stride = gridDim.x * blockDim.x;
    for (; i < n; i += stride) p[i] = 0;
}

// ---------------- K1: fused node GEMM ----------------
// out: fni[N,64] = nf @ W_ni ; fnj[N,64] = nf @ W_nj ; hproj[N,128] = nf @ W_node
__launch_bounds__(256, 2)
__global__ void k_node_gemm(const float* __restrict__ nf,
                            const float* __restrict__ Wni,
                            const float* __restrict__ Wnj,
                            const float* __restrict__ Wnode,
                            float* __restrict__ fni,
                            float* __restrict__ fnj,
                            float* __restrict__ hproj,
                            int Nn) {
    __shared__ float Alds[64][132];   // +4 pad: row-stride mod 32 = 4 -> 2-way max
    __shared__ float Wlds[128][64];
    int tid = threadIdx.x;
    int row0 = blockIdx.x * 64;
    // load A tile [64][128]
    #pragma unroll
    for (int t = 0; t < 8; t++) {
        int chunk = tid + t * 256;       // 2048 float4 chunks
        int r = chunk >> 5;
        int c4 = (chunk & 31) << 2;
        float4 v = make_float4(0.f, 0.f, 0.f, 0.f);
        int gr = row0 + r;
        if (gr < Nn) v = *(const float4*)&nf[(size_t)gr * INN + c4];
        Alds[r][c4 + 0] = v.x; Alds[r][c4 + 1] = v.y;
        Alds[r][c4 + 2] = v.z; Alds[r][c4 + 3] = v.w;
    }
    int tr = tid >> 4, tc = tid & 15;
    for (int p = 0; p < 4; p++) {
        const float* wsrc; int wstride, wcoff;
        float* dst; int dstride, dcoff;
        if (p == 0)      { wsrc = Wni;   wstride = 64;  wcoff = 0;  dst = fni;   dstride = 64;  dcoff = 0; }
        else if (p == 1) { wsrc = Wnj;   wstride = 64;  wcoff = 0;  dst = fnj;   dstride = 64;  dcoff = 0; }
        else if (p == 2) { wsrc = Wnode; wstride = 128; wcoff = 0;  dst = hproj; dstride = 128; dcoff = 0; }
        else             { wsrc = Wnode; wstride = 128; wcoff = 64; dst = hproj; dstride = 128; dcoff = 64; }
        __syncthreads();
        #pragma unroll
        for (int t = 0; t < 8; t++) {
            int chunk = tid + t * 256;   // 2048 float4 chunks of [128][64]
            int k = chunk >> 4;
            int c4 = (chunk & 15) << 2;
            float4 v = *(const float4*)&wsrc[(size_t)k * wstride + wcoff + c4];
            *(float4*)&Wlds[k][c4] = v;
        }
        __syncthreads();
        float acc[4][4];
        #pragma unroll
        for (int i = 0; i < 4; i++)
            #pragma unroll
            for (int j = 0; j < 4; j++) acc[i][j] = 0.f;
        for (int k = 0; k < 128; k++) {
            float4 b = *(float4*)&Wlds[k][tc << 2];
            #pragma unroll
            for (int i = 0; i < 4; i++) {
                float a = Alds[tr * 4 + i][k];
                acc[i][0] += a * b.x; acc[i][1] += a * b.y;
                acc[i][2] += a * b.z; acc[i][3] += a * b.w;
            }
        }
        #pragma unroll
        for (int i = 0; i < 4; i++) {
            int gr = row0 + tr * 4 + i;
            if (gr < Nn) {
                float4 v = make_float4(acc[i][0], acc[i][1], acc[i][2], acc[i][3]);
                *(float4*)&dst[(size_t)gr * dstride + dcoff + (tc << 2)] = v;
            }
        }
    }
}

// ---------------- K2: edge pass (wave per edge) ----------------
__launch_bounds__(256)
__global__ void k_edge(const float* __restrict__ efeats,
                       const int* __restrict__ src,
                       const int* __restrict__ dst,
                       const float* __restrict__ Wfij,   // [32][64]
                       const float* __restrict__ bias,   // [64]
                       const float* __restrict__ attn,   // [64]
                       const float* __restrict__ fni,
                       const float* __restrict__ fnj,
                       float* __restrict__ fout,         // [E,64]
                       float* __restrict__ exws,         // [E,4]
                       int* __restrict__ count,          // [N]
                       int Ee) {
    __shared__ float Wf[INE * HOE];
    __shared__ float bi[HOE];
    __shared__ float at[HOE];
    int tid = threadIdx.x;
    for (int t = tid; t < INE * HOE; t += 256) Wf[t] = Wfij[t];
    if (tid < HOE) { bi[tid] = bias[tid]; at[tid] = attn[tid]; }
    __syncthreads();
    int lane = tid & 63;
    int wid = (blockIdx.x * 256 + tid) >> 6;
    int nw = (gridDim.x * 256) >> 6;
    for (int e = wid; e < Ee; e += nw) {
        int s = src[e], d = dst[e];
        float fv = fni[(size_t)s * HOE + lane] + fnj[(size_t)d * HOE + lane] + bi[lane];
        float ef = efeats[(size_t)e * INE + (lane & 31)];
        float acc = 0.f;
        #pragma unroll
        for (int k = 0; k < INE; k++) {
            float ek = __shfl(ef, k, 64);
            acc += ek * Wf[k * HOE + lane];
        }
        fv += acc;
        fv = fv > 0.f ? fv : 0.01f * fv;                  // leaky relu
        fout[(size_t)e * HOE + lane] = fv;
        float pl = fv * at[lane];
        #pragma unroll
        for (int o = 8; o >= 1; o >>= 1) pl += __shfl_xor(pl, o, 64);
        if ((lane & 15) == 0) exws[(size_t)e * NH + (lane >> 4)] = __expf(pl);
        if (lane == 0) atomicAdd(&count[d], 1);
    }
}

// ---------------- K3a: per-chunk exclusive scan (chunks of 256) ----------------
__global__ void k_scan_chunks(const int* __restrict__ count,
                              int* __restrict__ chunkscan,
                              int* __restrict__ chunktot, int n) {
    __shared__ int tmp[256];
    int t = threadIdx.x;
    int i = blockIdx.x * 256 + t;
    int v = (i < n) ? count[i] : 0;
    tmp[t] = v;
    __syncthreads();
    for (int o = 1; o < 256; o <<= 1) {
        int x = (t >= o) ? tmp[t - o] : 0;
        __syncthreads();
        tmp[t] += x;
        __syncthreads();
    }
    if (i < n) chunkscan[i] = tmp[t] - v;   // exclusive within chunk
    if (t == 255) chunktot[blockIdx.x] = tmp[t];
}

// ---------------- K3b: scan chunk totals (single block, up to 1024 chunks) ---
__global__ void k_scan_tot(const int* __restrict__ tot, int* __restrict__ base, int nc) {
    __shared__ int tmp[1024];
    int t = threadIdx.x;
    int v = (t < nc) ? tot[t] : 0;
    tmp[t] = v;
    __syncthreads();
    for (int o = 1; o < 1024; o <<= 1) {
        int x = (t >= o) ? tmp[t - o] : 0;
        __syncthreads();
        tmp[t] += x;
        __syncthreads();
    }
    if (t < nc) base[t] = tmp[t] - v;       // exclusive
}

// ---------------- K3c: final offsets ----------------
__global__ void k_offsets(const int* __restrict__ chunkscan,
                          const int* __restrict__ chunkbase,
                          int* __restrict__ offsets, int Nn, int Ee) {
    int i = blockIdx.x * blockDim.x + threadIdx.x;
    if (i < Nn) offsets[i] = chunkscan[i] + chunkbase[i >> 8];
    if (i == 0) offsets[Nn] = Ee;
}

// ---------------- K4: fill CSR edge lists ----------------
__global__ void k_fill(const int* __restrict__ dst,
                       const int* __restrict__ offsets,
                       int* __restrict__ cursor,
                       int* __restrict__ eids, int Ee) {
    int i = blockIdx.x * blockDim.x + threadIdx.x;
    int stride = gridDim.x * blockDim.x;
    for (; i < Ee; i += stride) {
        int d = dst[i];
        int p = atomicAdd(&cursor[d], 1);
        eids[offsets[d] + p] = i;
    }
}

// ---------------- K5: node-centric softmax + weighted aggregation -----------
__launch_bounds__(256)
__global__ void k_node_out(const int* __restrict__ offsets,
                           const int* __restrict__ eids,
                           const int* __restrict__ src,
                           const float* __restrict__ exws,   // [E,4]
                           const float* __restrict__ hproj,  // [N,128]
                           float* __restrict__ hout,         // [N,128]
                           int Nn) {
    int lane = threadIdx.x & 63;
    int n = (blockIdx.x * 256 + threadIdx.x) >> 6;
    if (n >= Nn) return;
    int o0 = offsets[n], o1 = offsets[n + 1];
    // pass 1: per-head denominators
    float s0 = 0.f, s1 = 0.f, s2 = 0.f, s3 = 0.f;
    for (int i = o0; i < o1; i++) {
        int e = eids[i];
        float4 x = *(const float4*)&exws[(size_t)e * NH];
        s0 += x.x; s1 += x.y; s2 += x.z; s3 += x.w;
    }
    float r0 = s0 > 0.f ? 1.f / s0 : 0.f;
    float r1 = s1 > 0.f ? 1.f / s1 : 0.f;
    float r2 = s2 > 0.f ? 1.f / s2 : 0.f;
    float r3 = s3 > 0.f ? 1.f / s3 : 0.f;
    int hi = lane >> 5;                       // 0 or 1
    float rlo = (hi == 0) ? r0 : r1;          // head for component `lane`
    float rhi = (hi == 0) ? r2 : r3;          // head for component `lane+64`
    // pass 2: weighted accumulate
    float a0 = 0.f, a1 = 0.f;
    for (int i = o0; i < o1; i++) {
        int e = eids[i];
        int s = src[e];
        float4 x = *(const float4*)&exws[(size_t)e * NH];
        float exl = (hi == 0) ? x.x : x.y;
        float exh = (hi == 0) ? x.z : x.w;
        float alo = exl * rlo;
        float ahi = exh * rhi;
        a0 += hproj[(size_t)s * HON + lane] * alo;
        a1 += hproj[(size_t)s * HON + 64 + lane] * ahi;
    }
    hout[(size_t)n * HON + lane] = a0;
    hout[(size_t)n * HON + 64 + lane] = a1;
}

// ---------------- launcher ----------------
extern "C" void kernel_launch(void* const* d_in, const int* in_sizes, int n_in,
                              void* d_out, int out_size, void* d_ws, size_t ws_size,
                              hipStream_t stream) {
    const float* n_feats = (const float*)d_in[0];
    const float* e_feats = (const float*)d_in[1];
    const int*   src     = (const int*)d_in[2];
    const int*   dst     = (const int*)d_in[3];
    const float* W_ni    = (const float*)d_in[4];
    const float* W_nj    = (const float*)d_in[5];
    const float* W_fij   = (const float*)d_in[6];
    const float* bias_e  = (const float*)d_in[7];
    const float* attn    = (const float*)d_in[8];
    const float* W_node  = (const float*)d_in[9];

    const int Nn = in_sizes[0] / INN;
    const int Ee = in_sizes[2];

    float* hout = (float*)d_out;                       // [N,128]
    float* fout = (float*)d_out + (size_t)Nn * HON;    // [E,64]

    // workspace layout (256B aligned regions)
    char* ws = (char*)d_ws;
    size_t off = 0;
    auto alloc = [&](size_t bytes) {
        size_t o = off;
        off = (off + bytes + 255) & ~(size_t)255;
        return o;
    };
    size_t o_fni   = alloc((size_t)Nn * HOE * 4);
    size_t o_fnj   = alloc((size_t)Nn * HOE * 4);
    size_t o_hproj = alloc((size_t)Nn * HON * 4);
    size_t o_exws  = alloc((size_t)Ee * NH * 4);
    size_t o_eids  = alloc((size_t)Ee * 4);
    size_t o_count = alloc((size_t)Nn * 4);
    size_t o_curs  = alloc((size_t)Nn * 4);
    size_t o_offs  = alloc((size_t)(Nn + 1) * 4);
    size_t o_cscan = alloc((size_t)Nn * 4);
    size_t o_cbase = alloc((size_t)1024 * 4);
    (void)ws_size;

    float* fni   = (float*)(ws + o_fni);
    float* fnj   = (float*)(ws + o_fnj);
    float* hproj = (float*)(ws + o_hproj);
    float* exws  = (float*)(ws + o_exws);
    int* eids    = (int*)(ws + o_eids);
    int* count   = (int*)(ws + o_count);
    int* cursor  = (int*)(ws + o_curs);
    int* offsets = (int*)(ws + o_offs);
    int* cscan   = (int*)(ws + o_cscan);
    int* cbase   = (int*)(ws + o_cbase);

    int nchunks = (Nn + 255) / 256;

    // K0: zero counters
    k_zero_i32<<<(Nn + 255) / 256, 256, 0, stream>>>(count, Nn);
    k_zero_i32<<<(Nn + 255) / 256, 256, 0, stream>>>(cursor, Nn);

    // K1: node GEMMs
    k_node_gemm<<<(Nn + 63) / 64, 256, 0, stream>>>(
        n_feats, W_ni, W_nj, W_node, fni, fnj, hproj, Nn);

    // K2: edge pass (f_out + exp(logits) + degree count)
    k_edge<<<8192, 256, 0, stream>>>(
        e_feats, src, dst, W_fij, bias_e, attn, fni, fnj, fout, exws, count, Ee);

    // K3: exclusive scan of counts -> CSR offsets
    k_scan_chunks<<<nchunks, 256, 0, stream>>>(count, cscan, cbase /*reuse as tot*/, Nn);
    k_scan_tot<<<1, 1024, 0, stream>>>(cbase, cbase, nchunks);  // in-place: reads then writes same idx
    k_offsets<<<(Nn + 255) / 256, 256, 0, stream>>>(cscan, cbase, offsets, Nn, Ee);

    // K4: fill CSR
    k_fill<<<4096, 256, 0, stream>>>(dst, offsets, cursor, eids, Ee);

    // K5: node output
    k_node_out<<<(Nn + 3) / 4, 256, 0, stream>>>(
        offsets, eids, src, exws, hproj, hout, Nn);
}

// Round 2
// 758.926 us; speedup vs baseline: 1.6198x; 1.6198x over previous
//
#include <hip/hip_runtime.h>
#include <hip/hip_bf16.h>
#include <math.h>

#define NH 4      // heads
#define OE 16     // OUT_E
#define ON 32     // OUT_N
#define INN 128   // IN_N
#define INE 32    // IN_E
#define HOE 64    // NH*OE
#define HON 128   // NH*ON

__device__ __forceinline__ float readlane_f(float v, int k) {
    return __uint_as_float(__builtin_amdgcn_readlane(__float_as_uint(v), k));
}

// ---------------- K0: zero int32 buffer ----------------
__global__ void k_zero_i32(int* __restrict__ p, int n) {
    int i = blockIdx.x * blockDim.x + threadIdx.x;
    int stride = gridDim.x * blockDim.x;
    for (; i < n; i += stride) p[i] = 0;
}

// ---------------- K1: fused node GEMM ----------------
// out: fni[N,64] = nf @ W_ni ; fnj[N,64] = nf @ W_nj ; hproj[N,128] = nf @ W_node
__launch_bounds__(256, 2)
__global__ void k_node_gemm(const float* __restrict__ nf,
                            const float* __restrict__ Wni,
                            const float* __restrict__ Wnj,
                            const float* __restrict__ Wnode,
                            float* __restrict__ fni,
                            float* __restrict__ fnj,
                            float* __restrict__ hproj,
                            int Nn) {
    __shared__ float Alds[64][132];
    __shared__ float Wlds[128][64];
    int tid = threadIdx.x;
    int row0 = blockIdx.x * 64;
    #pragma unroll
    for (int t = 0; t < 8; t++) {
        int chunk = tid + t * 256;
        int r = chunk >> 5;
        int c4 = (chunk & 31) << 2;
        float4 v = make_float4(0.f, 0.f, 0.f, 0.f);
        int gr = row0 + r;
        if (gr < Nn) v = *(const float4*)&nf[(size_t)gr * INN + c4];
        Alds[r][c4 + 0] = v.x; Alds[r][c4 + 1] = v.y;
        Alds[r][c4 + 2] = v.z; Alds[r][c4 + 3] = v.w;
    }
    int tr = tid >> 4, tc = tid & 15;
    for (int p = 0; p < 4; p++) {
        const float* wsrc; int wstride, wcoff;
        float* dst; int dstride, dcoff;
        if (p == 0)      { wsrc = Wni;   wstride = 64;  wcoff = 0;  dst = fni;   dstride = 64;  dcoff = 0; }
        else if (p == 1) { wsrc = Wnj;   wstride = 64;  wcoff = 0;  dst = fnj;   dstride = 64;  dcoff = 0; }
        else if (p == 2) { wsrc = Wnode; wstride = 128; wcoff = 0;  dst = hproj; dstride = 128; dcoff = 0; }
        else             { wsrc = Wnode; wstride = 128; wcoff = 64; dst = hproj; dstride = 128; dcoff = 64; }
        __syncthreads();
        #pragma unroll
        for (int t = 0; t < 8; t++) {
            int chunk = tid + t * 256;
            int k = chunk >> 4;
            int c4 = (chunk & 15) << 2;
            float4 v = *(const float4*)&wsrc[(size_t)k * wstride + wcoff + c4];
            *(float4*)&Wlds[k][c4] = v;
        }
        __syncthreads();
        float acc[4][4];
        #pragma unroll
        for (int i = 0; i < 4; i++)
            #pragma unroll
            for (int j = 0; j < 4; j++) acc[i][j] = 0.f;
        for (int k = 0; k < 128; k++) {
            float4 b = *(float4*)&Wlds[k][tc << 2];
            #pragma unroll
            for (int i = 0; i < 4; i++) {
                float a = Alds[tr * 4 + i][k];
                acc[i][0] += a * b.x; acc[i][1] += a * b.y;
                acc[i][2] += a * b.z; acc[i][3] += a * b.w;
            }
        }
        #pragma unroll
        for (int i = 0; i < 4; i++) {
            int gr = row0 + tr * 4 + i;
            if (gr < Nn) {
                float4 v = make_float4(acc[i][0], acc[i][1], acc[i][2], acc[i][3]);
                *(float4*)&dst[(size_t)gr * dstride + dcoff + (tc << 2)] = v;
            }
        }
    }
}

// ---------------- K2: edge pass (wave per edge, zero LDS) ----------------
__launch_bounds__(256)
__global__ void k_edge(const float* __restrict__ efeats,
                       const int* __restrict__ src,
                       const int* __restrict__ dst,
                       const float* __restrict__ Wfij,   // [32][64]
                       const float* __restrict__ bias,   // [64]
                       const float* __restrict__ attn,   // [64]
                       const float* __restrict__ fni,
                       const float* __restrict__ fnj,
                       float* __restrict__ fout,         // [E,64]
                       float* __restrict__ exws,         // [E,4]
                       int* __restrict__ count,          // [N]
                       int Ee) {
    int tid = threadIdx.x;
    int lane = tid & 63;
    // W_fij column `lane` into registers (coalesced: each k reads one 256B row)
    float wf[32];
    #pragma unroll
    for (int k = 0; k < 32; k++) wf[k] = Wfij[k * HOE + lane];
    float bi = bias[lane];
    float at = attn[lane];
    int wid = (blockIdx.x * 256 + tid) >> 6;
    int nw = (gridDim.x * 256) >> 6;
    for (int e = wid; e < Ee; e += nw) {
        int s = src[e], d = dst[e];
        float ef = efeats[(size_t)e * INE + (lane & 31)];
        float fv = fni[(size_t)s * HOE + lane] + fnj[(size_t)d * HOE + lane] + bi;
        float acc = 0.f;
        #pragma unroll
        for (int k = 0; k < 32; k++) {
            acc += readlane_f(ef, k) * wf[k];   // uniform broadcast, no LDS pipe
        }
        fv += acc;
        fv = fv > 0.f ? fv : 0.01f * fv;                  // leaky relu
        fout[(size_t)e * HOE + lane] = fv;
        float pl = fv * at;
        #pragma unroll
        for (int o = 8; o >= 1; o >>= 1) pl += __shfl_xor(pl, o, 16);
        if ((lane & 15) == 0) exws[(size_t)e * NH + (lane >> 4)] = __expf(pl);
        if (lane == 0) atomicAdd(&count[d], 1);
    }
}

// ---------------- K3a: per-chunk exclusive scan (chunks of 256) ----------------
__global__ void k_scan_chunks(const int* __restrict__ count,
                              int* __restrict__ chunkscan,
                              int* __restrict__ chunktot, int n) {
    __shared__ int tmp[256];
    int t = threadIdx.x;
    int i = blockIdx.x * 256 + t;
    int v = (i < n) ? count[i] : 0;
    tmp[t] = v;
    __syncthreads();
    for (int o = 1; o < 256; o <<= 1) {
        int x = (t >= o) ? tmp[t - o] : 0;
        __syncthreads();
        tmp[t] += x;
        __syncthreads();
    }
    if (i < n) chunkscan[i] = tmp[t] - v;
    if (t == 255) chunktot[blockIdx.x] = tmp[t];
}

// ---------------- K3b: scan chunk totals (single block) ----------------
__global__ void k_scan_tot(const int* __restrict__ tot, int* __restrict__ base, int nc) {
    __shared__ int tmp[1024];
    int t = threadIdx.x;
    int v = (t < nc) ? tot[t] : 0;
    tmp[t] = v;
    __syncthreads();
    for (int o = 1; o < 1024; o <<= 1) {
        int x = (t >= o) ? tmp[t - o] : 0;
        __syncthreads();
        tmp[t] += x;
        __syncthreads();
    }
    if (t < nc) base[t] = tmp[t] - v;
}

// ---------------- K3c: final offsets ----------------
__global__ void k_offsets(const int* __restrict__ chunkscan,
                          const int* __restrict__ chunkbase,
                          int* __restrict__ offsets, int Nn, int Ee) {
    int i = blockIdx.x * blockDim.x + threadIdx.x;
    if (i < Nn) offsets[i] = chunkscan[i] + chunkbase[i >> 8];
    if (i == 0) offsets[Nn] = Ee;
}

// ---------------- K4: fill CSR edge lists ----------------
__global__ void k_fill(const int* __restrict__ dst,
                       const int* __restrict__ offsets,
                       int* __restrict__ cursor,
                       int* __restrict__ eids, int Ee) {
    int i = blockIdx.x * blockDim.x + threadIdx.x;
    int stride = gridDim.x * blockDim.x;
    for (; i < Ee; i += stride) {
        int d = dst[i];
        int p = atomicAdd(&cursor[d], 1);
        eids[offsets[d] + p] = i;
    }
}

// ---------------- K5: node-centric softmax + aggregation (single pass) -------
__launch_bounds__(256)
__global__ void k_node_out(const int* __restrict__ offsets,
                           const int* __restrict__ eids,
                           const int* __restrict__ srcv,
                           const float* __restrict__ exws,   // [E,4]
                           const float* __restrict__ hproj,  // [N,128]
                           float* __restrict__ hout,         // [N,128]
                           int Nn) {
    int lane = threadIdx.x & 63;
    int n = (blockIdx.x * 256 + threadIdx.x) >> 6;
    if (n >= Nn) return;
    int o0 = offsets[n], o1 = offsets[n + 1];
    int hi = lane >> 5;                       // 0 or 1
    float s0 = 0.f, s1 = 0.f, s2 = 0.f, s3 = 0.f;
    float a0 = 0.f, a1 = 0.f;
    for (int i0 = o0; i0 < o1; i0 += 64) {
        int nb = min(64, o1 - i0);
        int ve = 0, vs = 0;
        if (lane < nb) {
            ve = eids[i0 + lane];             // coalesced batch prefetch
            vs = srcv[ve];
        }
        for (int j = 0; j < nb; j++) {
            int e = __builtin_amdgcn_readlane(ve, j);   // SGPR-uniform
            int s = __builtin_amdgcn_readlane(vs, j);   // SGPR-uniform base
            float4 x = *(const float4*)&exws[(size_t)e * NH];
            s0 += x.x; s1 += x.y; s2 += x.z; s3 += x.w;
            float exl = (hi == 0) ? x.x : x.y;
            float exh = (hi == 0) ? x.z : x.w;
            a0 += hproj[(size_t)s * HON + lane] * exl;
            a1 += hproj[(size_t)s * HON + 64 + lane] * exh;
        }
    }
    float r0 = s0 > 0.f ? 1.f / s0 : 0.f;
    float r1 = s1 > 0.f ? 1.f / s1 : 0.f;
    float r2 = s2 > 0.f ? 1.f / s2 : 0.f;
    float r3 = s3 > 0.f ? 1.f / s3 : 0.f;
    float rlo = (hi == 0) ? r0 : r1;
    float rhi = (hi == 0) ? r2 : r3;
    hout[(size_t)n * HON + lane] = a0 * rlo;
    hout[(size_t)n * HON + 64 + lane] = a1 * rhi;
}

// ---------------- launcher ----------------
extern "C" void kernel_launch(void* const* d_in, const int* in_sizes, int n_in,
                              void* d_out, int out_size, void* d_ws, size_t ws_size,
                              hipStream_t stream) {
    const float* n_feats = (const float*)d_in[0];
    const float* e_feats = (const float*)d_in[1];
    const int*   src     = (const int*)d_in[2];
    const int*   dst     = (const int*)d_in[3];
    const float* W_ni    = (const float*)d_in[4];
    const float* W_nj    = (const float*)d_in[5];
    const float* W_fij   = (const float*)d_in[6];
    const float* bias_e  = (const float*)d_in[7];
    const float* attn    = (const float*)d_in[8];
    const float* W_node  = (const float*)d_in[9];

    const int Nn = in_sizes[0] / INN;
    const int Ee = in_sizes[2];

    float* hout = (float*)d_out;                       // [N,128]
    float* fout = (float*)d_out + (size_t)Nn * HON;    // [E,64]

    char* ws = (char*)d_ws;
    size_t off = 0;
    auto alloc = [&](size_t bytes) {
        size_t o = off;
        off = (off + bytes + 255) & ~(size_t)255;
        return o;
    };
    size_t o_fni   = alloc((size_t)Nn * HOE * 4);
    size_t o_fnj   = alloc((size_t)Nn * HOE * 4);
    size_t o_hproj = alloc((size_t)Nn * HON * 4);
    size_t o_exws  = alloc((size_t)Ee * NH * 4);
    size_t o_eids  = alloc((size_t)Ee * 4);
    size_t o_count = alloc((size_t)Nn * 4);
    size_t o_curs  = alloc((size_t)Nn * 4);
    size_t o_offs  = alloc((size_t)(Nn + 1) * 4);
    size_t o_cscan = alloc((size_t)Nn * 4);
    size_t o_cbase = alloc((size_t)1024 * 4);
    (void)ws_size;

    float* fni   = (float*)(ws + o_fni);
    float* fnj   = (float*)(ws + o_fnj);
    float* hproj = (float*)(ws + o_hproj);
    float* exws  = (float*)(ws + o_exws);
    int* eids    = (int*)(ws + o_eids);
    int* count   = (int*)(ws + o_count);
    int* cursor  = (int*)(ws + o_curs);
    int* offsets = (int*)(ws + o_offs);
    int* cscan   = (int*)(ws + o_cscan);
    int* cbase   = (int*)(ws + o_cbase);

    int nchunks = (Nn + 255) / 256;

    k_zero_i32<<<(Nn + 255) / 256, 256, 0, stream>>>(count, Nn);
    k_zero_i32<<<(Nn + 255) / 256, 256, 0, stream>>>(cursor, Nn);

    k_node_gemm<<<(Nn + 63) / 64, 256, 0, stream>>>(
        n_feats, W_ni, W_nj, W_node, fni, fnj, hproj, Nn);

    k_edge<<<8192, 256, 0, stream>>>(
        e_feats, src, dst, W_fij, bias_e, attn, fni, fnj, fout, exws, count, Ee);

    k_scan_chunks<<<nchunks, 256, 0, stream>>>(count, cscan, cbase, Nn);
    k_scan_tot<<<1, 1024, 0, stream>>>(cbase, cbase, nchunks);
    k_offsets<<<(Nn + 255) / 256, 256, 0, stream>>>(cscan, cbase, offsets, Nn, Ee);

    k_fill<<<4096, 256, 0, stream>>>(dst, offsets, cursor, eids, Ee);

    k_node_out<<<(Nn + 3) / 4, 256, 0, stream>>>(
        offsets, eids, src, exws, hproj, hout, Nn);
}